// Round 18
// baseline (2469.438 us; speedup 1.0000x reference)
//
#include <hip/hip_runtime.h>
#include <hip/hip_bf16.h>
#include <math.h>

#define B_ROWS   32768
#define NSTEPS   5
#define EPS_BN   1e-5f
#define RELAX_C  1.5f
#define SQRT_HALF 0.70710678118654752440f

typedef _Float16 f16;
typedef _Float16 f16x4 __attribute__((ext_vector_type(4)));
typedef _Float16 f16x8 __attribute__((ext_vector_type(8)));
typedef float    f32x4 __attribute__((ext_vector_type(4)));

// GLU pairing permutation: permuted col c -> source col.
__device__ __forceinline__ int glu_perm2(int c) {
    int g = c >> 5, o = c & 31;
    return (o < 16) ? (g * 16 + o) : (g * 16 + (o - 16) + 256);
}

__device__ __forceinline__ void gload16(const void* g, void* l) {
    __builtin_amdgcn_global_load_lds(
        (const __attribute__((address_space(1))) unsigned int*)g,
        (__attribute__((address_space(3))) unsigned int*)l, 16, 0, 0);
}

// ---------------- merged prep (single dispatch) ----------------
__global__ void prep_all(
    const float* __restrict__ bn0_g, const float* __restrict__ bn0_b,
    const float* __restrict__ bn0_m, const float* __restrict__ bn0_v,
    const float* __restrict__ ft_g, const float* __restrict__ ft_b,
    const float* __restrict__ ft_m, const float* __restrict__ ft_v,
    const float* __restrict__ att_g, const float* __restrict__ att_b,
    const float* __restrict__ att_m, const float* __restrict__ att_v,
    const float* __restrict__ Ws0, const float* __restrict__ Ws1,
    const float* __restrict__ Wu,  const float* __restrict__ Wat,
    const float* __restrict__ features,
    float* __restrict__ ftS, float* __restrict__ ftH,
    float* __restrict__ attS, float* __restrict__ attH,
    f16* __restrict__ ws0, f16* __restrict__ ws1,
    f16* __restrict__ wu,  f16* __restrict__ wat,
    f16* __restrict__ feats, float* __restrict__ oacc,
    unsigned int* __restrict__ gcnt)
{
    const int blk = blockIdx.x;
    if (blk < 60) {
        int idx = blk * 256 + threadIdx.x;
        if (idx < 24 * 512) {
            int tb = idx >> 9;
            int c = idx & 511;
            int src = tb * 512 + glu_perm2(c);
            float s = ft_g[src] * rsqrtf(ft_v[src] + EPS_BN);
            ftS[idx] = s;
            ftH[idx] = ft_b[src] - ft_m[src] * s;
        } else if (idx < 24 * 512 + 5 * 512) {
            int q = idx - 24 * 512;
            float s = att_g[q] * rsqrtf(att_v[q] + EPS_BN);
            attS[q] = s;
            attH[q] = att_b[q] - att_m[q] * s;
        }
    } else if (blk < 9020) {
        int i = (blk - 60) * 256 + threadIdx.x;
        if (i < 262144) {                        // ws0: [512][512]
            int n = i >> 9, k = i & 511;
            ws0[i] = (f16)Ws0[(k << 9) + glu_perm2(n)];
        } else if (i < 393216) {                 // ws1: [512][256]
            int j = i - 262144;
            int n = j >> 8, k = j & 255;
            ws1[j] = (f16)Ws1[(k << 9) + glu_perm2(n)];
        } else if (i < 1966080) {                // wu: 12 x [512][256]
            int j = i - 393216;
            int mat = j >> 17;
            int r = j & 131071;
            int n = r >> 8, k = r & 255;
            wu[j] = (f16)Wu[(mat << 17) + (k << 9) + glu_perm2(n)];
        } else if (i < 2293760) {                // wat: 5 x [512][128]
            int j = i - 1966080;
            int mat = j >> 16;
            int r = j & 65535;
            int n = r >> 7, k = r & 127;
            wat[j] = (f16)Wat[(mat << 16) + (k << 9) + n];
        }
    } else if (blk < 29500) {
        const int b = blk - 9020;
        if (b < 16384) {
            int i = b * 256 + threadIdx.x;       // B*512/4 elems of float4
            int base = i * 4;
            int c = base & 511;
            float4 xv = *(const float4*)(features + base);
            f16x4 hv;
            float s0 = bn0_g[c]     * rsqrtf(bn0_v[c]     + EPS_BN);
            float s1 = bn0_g[c + 1] * rsqrtf(bn0_v[c + 1] + EPS_BN);
            float s2 = bn0_g[c + 2] * rsqrtf(bn0_v[c + 2] + EPS_BN);
            float s3 = bn0_g[c + 3] * rsqrtf(bn0_v[c + 3] + EPS_BN);
            hv.x = (f16)((xv.x - bn0_m[c])     * s0 + bn0_b[c]);
            hv.y = (f16)((xv.y - bn0_m[c + 1]) * s1 + bn0_b[c + 1]);
            hv.z = (f16)((xv.z - bn0_m[c + 2]) * s2 + bn0_b[c + 2]);
            hv.w = (f16)((xv.w - bn0_m[c + 3]) * s3 + bn0_b[c + 3]);
            *(f16x4*)(feats + base) = hv;
        } else {
            int i = (b - 16384) * 256 + threadIdx.x;   // B*128/4 float4
            ((float4*)oacc)[i] = make_float4(0.f, 0.f, 0.f, 0.f);
        }
    } else {
        if (threadIdx.x < 128) gcnt[threadIdx.x] = 0u;   // gang barrier counters
    }
}

// ---------------- gang barrier (4 blocks, device-scope) ----------------
__device__ __forceinline__ void gbar(unsigned int* cnt, unsigned int tgt) {
    __syncthreads();                     // all waves' work done; vmcnt drained
    if (threadIdx.x == 0) {
        __threadfence();                 // release: stores visible device-wide
        atomicAdd(cnt, 1u);
        while (atomicAdd(cnt, 0u) < tgt)
            __builtin_amdgcn_s_sleep(8);
        __threadfence();                 // acquire: invalidate stale caches
    }
    __syncthreads();
}

// ---------------- conveyor GEMM stage (R15-proven inner loop, runtime mode) ----------------
// 8 waves (4 row x 2 col, 64x64), tile 256 rows x 128 cols, 3-slot x 24KB ring,
// counted vmcnt(3). mode 0: out=glu(bn(A@W)); 1: +res*sqrt(.5);
// 2: mode1, oc>=128 -> outp[B][128], oc<128 -> oa += relu (if oa).
__device__ __forceinline__ void gemm_stage(
    char* __restrict__ smem,
    const f16* __restrict__ A, const int ldA, const int NT,
    const f16* __restrict__ B,
    const float* __restrict__ scale, const float* __restrict__ shift,
    const f16* __restrict__ res,
    f16* __restrict__ outp, float* __restrict__ oa,
    const int mode, const int row0, const int bcol)
{
    const int K    = NT * 32;
    const int tid  = threadIdx.x;
    const int lane = tid & 63;
    const int w    = tid >> 6;
    const int wm   = w >> 1;             // 0..3
    const int wn   = w & 1;              // 0..1
    const int lr   = lane & 15;
    const int lh   = lane >> 4;

    // 24 chunks of 1KB per stage: 0..15 = A rows (16x16), 16..23 = B rows.
    const int c0 = 3 * w, c1 = 3 * w + 1, c2 = 3 * w + 2;
    const bool a0 = c0 < 16, a1 = c1 < 16, a2 = c2 < 16;
    const char* p0 = a0 ? (const char*)(A + (size_t)(row0 + c0 * 16 + lr) * ldA + lh * 8)
                        : (const char*)(B + (size_t)(bcol + (c0 - 16) * 16 + lr) * K + lh * 8);
    const char* p1 = a1 ? (const char*)(A + (size_t)(row0 + c1 * 16 + lr) * ldA + lh * 8)
                        : (const char*)(B + (size_t)(bcol + (c1 - 16) * 16 + lr) * K + lh * 8);
    const char* p2 = a2 ? (const char*)(A + (size_t)(row0 + c2 * 16 + lr) * ldA + lh * 8)
                        : (const char*)(B + (size_t)(bcol + (c2 - 16) * 16 + lr) * K + lh * 8);
    const int d0 = c0 * 1024, d1 = c1 * 1024, d2 = c2 * 1024;

    f32x4 acc[4][4];
    #pragma unroll
    for (int m = 0; m < 4; ++m)
        #pragma unroll
        for (int n = 0; n < 4; ++n)
            acc[m][n] = f32x4{0.f, 0.f, 0.f, 0.f};

    auto STAGE = [&](int s) {
        const int ko = s * 64;                 // 32 f16 = 64 bytes per k-step
        char* ring = smem + (s % 3) * 24576;
        gload16(p0 + ko, ring + d0);
        gload16(p1 + ko, ring + d1);
        gload16(p2 + ko, ring + d2);
    };

    STAGE(0); STAGE(1);

    for (int s = 0; s < NT; ++s) {
        if (s + 1 < NT) asm volatile("s_waitcnt vmcnt(3)" ::: "memory");
        else            asm volatile("s_waitcnt vmcnt(0)" ::: "memory");
        __builtin_amdgcn_s_barrier();
        asm volatile("" ::: "memory");         // pin ds_reads below barrier
        if (s + 2 < NT) STAGE(s + 2);

        const char* L = smem + (s % 3) * 24576;
        f16x8 a[4], b[4];
        #pragma unroll
        for (int m = 0; m < 4; ++m)
            a[m] = *(const f16x8*)(L + (wm * 4 + m) * 1024 + lane * 16);
        #pragma unroll
        for (int n = 0; n < 4; ++n)
            b[n] = *(const f16x8*)(L + 16384 + (wn * 4 + n) * 1024 + lane * 16);
        __builtin_amdgcn_s_setprio(1);
        #pragma unroll
        for (int n = 0; n < 4; ++n)
            #pragma unroll
            for (int m = 0; m < 4; ++m)
                acc[m][n] = __builtin_amdgcn_mfma_f32_16x16x32_f16(a[m], b[n], acc[m][n], 0, 0, 0);
        __builtin_amdgcn_s_setprio(0);
    }

    // epilogue: fragment row' = (lane>>4)*4+r, col' = lane&15; GLU in-lane (permuted W)
    const int rbase = row0 + wm * 64;
    #pragma unroll
    for (int p = 0; p < 2; ++p) {
        const int cb = bcol + wn * 64 + p * 32;
        const float sA = scale[cb + lr],      hA = shift[cb + lr];
        const float sB = scale[cb + 16 + lr], hB = shift[cb + 16 + lr];
        const int oc = (cb >> 1) + lr;
        #pragma unroll
        for (int m = 0; m < 4; ++m) {
            #pragma unroll
            for (int r = 0; r < 4; ++r) {
                const int row = rbase + m * 16 + lh * 4 + r;
                float y0 = acc[m][2 * p][r]     * sA + hA;
                float y1 = acc[m][2 * p + 1][r] * sB + hB;
                float val = y0 / (1.f + expf(-y1));
                if (mode >= 1)
                    val += SQRT_HALF * (float)res[(size_t)row * 256 + oc];
                if (mode <= 1) {
                    outp[(size_t)row * 256 + oc] = (f16)val;
                } else {
                    if (oc < 128) {
                        if (oa) oa[(size_t)row * 128 + oc] += fmaxf(val, 0.f);
                    } else {
                        outp[(size_t)row * 128 + (oc - 128)] = (f16)val;
                    }
                }
            }
        }
    }
}

// ---------------- attention + sparsemax stage (R15-proven body) ----------------
__device__ __forceinline__ void att_stage(
    char* __restrict__ smem,
    const f16* __restrict__ A,               // xhalf [B][128]
    const f16* __restrict__ Bw,              // [512][128] f16
    const float* __restrict__ scale, const float* __restrict__ shift,
    const f16* __restrict__ feats,
    f16* __restrict__ prior,
    float* __restrict__ mask_out,
    f16* __restrict__ mf,
    const int brow, const int use_prior)
{
    f16* attLds = (f16*)smem;                // 64 KB of the 72KB buffer
    const int tid  = threadIdx.x;
    const int lane = tid & 63;
    const int w    = tid >> 6;               // 0..7
    const int lr   = lane & 15;
    const int lk   = (lane >> 4) * 8;

    f32x4 acc[4][4];
    #pragma unroll
    for (int m = 0; m < 4; ++m)
        #pragma unroll
        for (int n = 0; n < 4; ++n)
            acc[m][n] = f32x4{0.f, 0.f, 0.f, 0.f};

    const f16* pa = A + (size_t)(brow + lr) * 128 + lk;
    const f16* pb = Bw + (size_t)(w * 64 + lr) * 128 + lk;

    #pragma unroll
    for (int t = 0; t < 4; ++t) {
        f16x8 a[4], b[4];
        #pragma unroll
        for (int m = 0; m < 4; ++m) a[m] = *(const f16x8*)(pa + m * 16 * 128 + t * 32);
        #pragma unroll
        for (int n = 0; n < 4; ++n) b[n] = *(const f16x8*)(pb + n * 16 * 128 + t * 32);
        __builtin_amdgcn_s_setprio(1);
        #pragma unroll
        for (int n = 0; n < 4; ++n)
            #pragma unroll
            for (int m = 0; m < 4; ++m)
                acc[m][n] = __builtin_amdgcn_mfma_f32_16x16x32_f16(a[m], b[n], acc[m][n], 0, 0, 0);
        __builtin_amdgcn_s_setprio(0);
    }

    __syncthreads();     // smem handoff from previous gemm stage usage
    #pragma unroll
    for (int n = 0; n < 4; ++n) {
        const int col = w * 64 + n * 16 + lr;
        const float s = scale[col], h = shift[col];
        #pragma unroll
        for (int m = 0; m < 4; ++m) {
            const int r0 = m * 16 + (lane >> 4) * 4;
            #pragma unroll
            for (int r = 0; r < 4; ++r)
                attLds[(r0 + r) * 512 + col] = (f16)(acc[m][n][r] * s + h);
        }
    }
    __syncthreads();

    // phase 2: wave w rows w*8..w*8+7; lane owns cols [8*lane, 8*lane+8)
    const int cb8 = lane * 8;
    for (int rr = 0; rr < 8; ++rr) {
        const int row = w * 8 + rr;
        const int grow = brow + row;
        const size_t g8 = (size_t)grow * 512 + cb8;

        float z[8], pr[8];
        f16x8 prv;
        if (use_prior) prv = *(const f16x8*)(prior + g8);
        f16x8 zv = *(const f16x8*)(&attLds[row * 512 + cb8]);
        #pragma unroll
        for (int j = 0; j < 8; ++j) {
            pr[j] = use_prior ? (float)prv[j] : 1.0f;
            z[j] = (float)zv[j] * pr[j];
        }
        float mx = z[0];
        #pragma unroll
        for (int j = 1; j < 8; ++j) mx = fmaxf(mx, z[j]);
        #pragma unroll
        for (int off = 32; off; off >>= 1) mx = fmaxf(mx, __shfl_xor(mx, off));

        float tau = mx - 1.0f;
        for (int it = 0; it < 20; ++it) {
            float s = 0.f, c = 0.f;
            #pragma unroll
            for (int j = 0; j < 8; ++j) {
                float dz = z[j] - tau;
                if (dz > 0.f) { s += dz; c += 1.f; }
            }
            #pragma unroll
            for (int off = 32; off; off >>= 1) {
                s += __shfl_xor(s, off);
                c += __shfl_xor(c, off);
            }
            float tn = tau + (s - 1.0f) / c;
            if (!(tn > tau)) break;
            tau = tn;
        }

        float mk[8];
        f16x8 pnew, mfv;
        f16x8 fv = *(const f16x8*)(feats + g8);
        #pragma unroll
        for (int j = 0; j < 8; ++j) {
            mk[j] = fmaxf(z[j] - tau, 0.f);
            pnew[j] = (f16)(pr[j] * (RELAX_C - mk[j]));
            mfv[j] = (f16)(mk[j] * (float)fv[j]);
        }
        f32x4 m0 = {mk[0], mk[1], mk[2], mk[3]};
        f32x4 m1 = {mk[4], mk[5], mk[6], mk[7]};
        __builtin_nontemporal_store(m0, (f32x4*)(mask_out + g8));
        __builtin_nontemporal_store(m1, (f32x4*)(mask_out + g8 + 4));
        *(f16x8*)(prior + g8) = pnew;
        *(f16x8*)(mf + g8) = mfv;
    }
}

// ---------------- persistent gang-pipelined kernel ----------------
// 512 blocks = 128 gangs of 4; gang owns a 256-row panel and runs the whole
// pipeline (6 transformers + 5 att steps) with only 4-block gang barriers.
// All data deps are panel-local (verified stage by stage).
__global__ __launch_bounds__(512, 4) void tabnet_persist(
    const f16* __restrict__ feats, f16* __restrict__ mf,
    f16* __restrict__ ub, f16* __restrict__ vb,
    f16* __restrict__ xh, f16* __restrict__ prior, float* __restrict__ oacc,
    const f16* __restrict__ ws0, const f16* __restrict__ ws1,
    const f16* __restrict__ wu,  const f16* __restrict__ wat,
    const float* __restrict__ ftS, const float* __restrict__ ftH,
    const float* __restrict__ attS, const float* __restrict__ attH,
    float* __restrict__ out, unsigned int* __restrict__ gcnt)
{
    __shared__ __align__(16) char smem[3 * 24576];
    const int d    = blockIdx.x;
    const int bid  = (d & 7) * 64 + (d >> 3);    // XCD-bijective; gang on one XCD
    const int gang = bid >> 2;
    const int j    = bid & 3;
    const int row0 = gang * 256;
    const int bcol = j * 128;
    unsigned int* cnt = gcnt + gang;
    unsigned int ep = 0;

    for (int t = 0; t < 6; ++t) {
        const f16* in0 = (t == 0) ? feats : mf;
        #pragma unroll 1
        for (int g = 0; g < 4; ++g) {
            const f16* Ag  = (g == 0) ? in0 : ((g == 2) ? vb : ub);
            const int ldA  = (g == 0) ? 512 : 256;
            const int NT   = (g == 0) ? 16 : 8;
            const f16* Bw  = (g == 0) ? ws0 : (g == 1) ? ws1
                            : wu + (size_t)(t * 2 + (g - 2)) * 131072;
            f16* outp      = (g == 1) ? vb : ((g == 3) ? xh : ub);
            const int mode = (g == 0) ? 0 : ((g == 3) ? 2 : 1);
            float* oa      = (g == 3 && t > 0) ? oacc : nullptr;
            gemm_stage(smem, Ag, ldA, NT, Bw,
                       ftS + (t * 4 + g) * 512, ftH + (t * 4 + g) * 512,
                       Ag, outp, oa, mode, row0, bcol);
            gbar(cnt, 4u * ++ep);
        }
        if (t < 5) {
            att_stage(smem, xh, wat + (size_t)t * 65536,
                      attS + t * 512, attH + t * 512,
                      feats, prior, out + 4194304 + (size_t)t * 16777216, mf,
                      row0 + j * 64, t != 0);
            gbar(cnt, 4u * ++ep);
        }
    }
}

// ---------------- final fp32 SIMT GEMM (K=128, N=128) ----------------
__global__ __launch_bounds__(256) void gemm_f32_final(
    const float* __restrict__ A,
    const float* __restrict__ W,
    const float* __restrict__ bias,
    float* __restrict__ out)
{
    __shared__ float As[16][128];
    __shared__ float Bs[16][128];
    const int tid = threadIdx.x;
    const int tm = tid >> 4, tn = tid & 15;
    const int brow = blockIdx.x * 128;
    float acc[8][8] = {};
    for (int k0 = 0; k0 < 128; k0 += 16) {
        #pragma unroll
        for (int i = 0; i < 2; ++i) {
            int f = tid + i * 256;
            int row = f >> 2, kq = (f & 3) << 2;
            float4 av = *(const float4*)(A + (size_t)(brow + row) * 128 + k0 + kq);
            As[kq + 0][row] = av.x;
            As[kq + 1][row] = av.y;
            As[kq + 2][row] = av.z;
            As[kq + 3][row] = av.w;
            int kr = f >> 5, nq = (f & 31) << 2;
            *(float4*)(&Bs[kr][nq]) = *(const float4*)(W + (size_t)(k0 + kr) * 128 + nq);
        }
        __syncthreads();
        #pragma unroll
        for (int kk = 0; kk < 16; ++kk) {
            float a[8], b[8];
            *(float4*)(a)     = *(const float4*)(&As[kk][tm * 8]);
            *(float4*)(a + 4) = *(const float4*)(&As[kk][tm * 8 + 4]);
            *(float4*)(b)     = *(const float4*)(&Bs[kk][tn * 8]);
            *(float4*)(b + 4) = *(const float4*)(&Bs[kk][tn * 8 + 4]);
            #pragma unroll
            for (int i = 0; i < 8; ++i)
                #pragma unroll
                for (int j = 0; j < 8; ++j)
                    acc[i][j] += a[i] * b[j];
        }
        __syncthreads();
    }
    #pragma unroll
    for (int i = 0; i < 8; ++i) {
        int row = brow + tm * 8 + i;
        #pragma unroll
        for (int j = 0; j < 8; ++j)
            out[(size_t)row * 128 + tn * 8 + j] = acc[i][j] + bias[tn * 8 + j];
    }
}

// ---------------- launch ----------------
extern "C" void kernel_launch(void* const* d_in, const int* in_sizes, int n_in,
                              void* d_out, int out_size, void* d_ws, size_t ws_size,
                              hipStream_t stream)
{
    const float* features = (const float*)d_in[0];
    const float* bn0_g = (const float*)d_in[1];
    const float* bn0_b = (const float*)d_in[2];
    const float* bn0_m = (const float*)d_in[3];
    const float* bn0_v = (const float*)d_in[4];
    const float* Ws0   = (const float*)d_in[5];
    const float* Ws1   = (const float*)d_in[6];
    const float* Wu    = (const float*)d_in[7];
    const float* ft_g  = (const float*)d_in[8];
    const float* ft_b  = (const float*)d_in[9];
    const float* ft_m  = (const float*)d_in[10];
    const float* ft_v  = (const float*)d_in[11];
    const float* W_att = (const float*)d_in[12];
    const float* att_g = (const float*)d_in[13];
    const float* att_b = (const float*)d_in[14];
    const float* att_m = (const float*)d_in[15];
    const float* att_v = (const float*)d_in[16];
    const float* Wf    = (const float*)d_in[17];
    const float* bf    = (const float*)d_in[18];
    float* out = (float*)d_out;

    // ---- ws layout (bytes) ----
    char* wp = (char*)d_ws;
    auto alloc = [&](size_t bytes) { char* r = wp; wp += (bytes + 255) & ~(size_t)255; return r; };
    const size_t BR = B_ROWS;
    f16* feats  = (f16*)alloc(BR * 512 * 2);
    f16* mfbuf  = (f16*)alloc(BR * 512 * 2);
    f16* ubuf   = (f16*)alloc(BR * 256 * 2);
    f16* vbuf   = (f16*)alloc(BR * 256 * 2);
    f16* xhalf  = (f16*)alloc(BR * 128 * 2);
    f16* prior  = (f16*)alloc(BR * 512 * 2);
    float* oacc  = (float*)alloc(BR * 128 * 4);
    f16* ws0  = (f16*)alloc(512 * 512 * 2);
    f16* ws1  = (f16*)alloc(512 * 256 * 2);
    f16* wu   = (f16*)alloc((size_t)12 * 512 * 256 * 2);
    f16* wat  = (f16*)alloc((size_t)5 * 512 * 128 * 2);
    float* ftS  = (float*)alloc(24 * 512 * 4);
    float* ftH  = (float*)alloc(24 * 512 * 4);
    float* attS = (float*)alloc(5 * 512 * 4);
    float* attH = (float*)alloc(5 * 512 * 4);
    unsigned int* gcnt = (unsigned int*)alloc(128 * 4);

    // ---- prep (1 dispatch; also zeroes gang counters) ----
    prep_all<<<29501, 256, 0, stream>>>(
        bn0_g, bn0_b, bn0_m, bn0_v, ft_g, ft_b, ft_m, ft_v,
        att_g, att_b, att_m, att_v, Ws0, Ws1, Wu, W_att, features,
        ftS, ftH, attS, attH, ws0, ws1, wu, wat, feats, oacc, gcnt);

    // ---- whole pipeline in one persistent dispatch ----
    tabnet_persist<<<512, 512, 0, stream>>>(
        feats, mfbuf, ubuf, vbuf, xhalf, prior, oacc,
        ws0, ws1, wu, wat, ftS, ftH, attS, attH, out, gcnt);

    // ---- final = oacc @ Wf + bf ----
    gemm_f32_final<<<B_ROWS / 128, 256, 0, stream>>>(oacc, Wf, bf, out);
}

// Round 19
// 929.202 us; speedup vs baseline: 2.6576x; 2.6576x over previous
//
#include <hip/hip_runtime.h>
#include <hip/hip_bf16.h>
#include <math.h>

#define B_ROWS   32768
#define NSTEPS   5
#define EPS_BN   1e-5f
#define RELAX_C  1.5f
#define SQRT_HALF 0.70710678118654752440f

typedef _Float16 f16;
typedef _Float16 f16x4 __attribute__((ext_vector_type(4)));
typedef _Float16 f16x8 __attribute__((ext_vector_type(8)));
typedef float    f32x4 __attribute__((ext_vector_type(4)));

// GLU pairing permutation: permuted col c -> source col.
// Within each 32-col group g: positions 0..15 = y0 (src g*16+o), 16..31 = gate (src g*16+(o-16)+256).
__device__ __forceinline__ int glu_perm2(int c) {
    int g = c >> 5, o = c & 31;
    return (o < 16) ? (g * 16 + o) : (g * 16 + (o - 16) + 256);
}

__device__ __forceinline__ void gload16(const void* g, void* l) {
    __builtin_amdgcn_global_load_lds(
        (const __attribute__((address_space(1))) unsigned int*)g,
        (__attribute__((address_space(3))) unsigned int*)l, 16, 0, 0);
}

// ---------------- merged prep (single dispatch) ----------------
__global__ void prep_all(
    const float* __restrict__ bn0_g, const float* __restrict__ bn0_b,
    const float* __restrict__ bn0_m, const float* __restrict__ bn0_v,
    const float* __restrict__ ft_g, const float* __restrict__ ft_b,
    const float* __restrict__ ft_m, const float* __restrict__ ft_v,
    const float* __restrict__ att_g, const float* __restrict__ att_b,
    const float* __restrict__ att_m, const float* __restrict__ att_v,
    const float* __restrict__ Ws0, const float* __restrict__ Ws1,
    const float* __restrict__ Wu,  const float* __restrict__ Wat,
    const float* __restrict__ features,
    float* __restrict__ ftS, float* __restrict__ ftH,
    float* __restrict__ attS, float* __restrict__ attH,
    f16* __restrict__ ws0, f16* __restrict__ ws1,
    f16* __restrict__ wu,  f16* __restrict__ wat,
    f16* __restrict__ feats, float* __restrict__ oacc)
{
    const int blk = blockIdx.x;
    if (blk < 60) {
        int idx = blk * 256 + threadIdx.x;
        if (idx < 24 * 512) {
            int tb = idx >> 9;
            int c = idx & 511;
            int src = tb * 512 + glu_perm2(c);
            float s = ft_g[src] * rsqrtf(ft_v[src] + EPS_BN);
            ftS[idx] = s;
            ftH[idx] = ft_b[src] - ft_m[src] * s;
        } else if (idx < 24 * 512 + 5 * 512) {
            int q = idx - 24 * 512;
            float s = att_g[q] * rsqrtf(att_v[q] + EPS_BN);
            attS[q] = s;
            attH[q] = att_b[q] - att_m[q] * s;
        }
    } else if (blk < 9020) {
        int i = (blk - 60) * 256 + threadIdx.x;
        if (i < 262144) {                        // ws0: [512][512]
            int n = i >> 9, k = i & 511;
            ws0[i] = (f16)Ws0[(k << 9) + glu_perm2(n)];
        } else if (i < 393216) {                 // ws1: [512][256]
            int j = i - 262144;
            int n = j >> 8, k = j & 255;
            ws1[j] = (f16)Ws1[(k << 9) + glu_perm2(n)];
        } else if (i < 1966080) {                // wu: 12 x [512][256]
            int j = i - 393216;
            int mat = j >> 17;
            int r = j & 131071;
            int n = r >> 8, k = r & 255;
            wu[j] = (f16)Wu[(mat << 17) + (k << 9) + glu_perm2(n)];
        } else if (i < 2293760) {                // wat: 5 x [512][128]
            int j = i - 1966080;
            int mat = j >> 16;
            int r = j & 65535;
            int n = r >> 7, k = r & 127;
            wat[j] = (f16)Wat[(mat << 16) + (k << 9) + n];
        }
    } else {
        const int b = blk - 9020;
        if (b < 16384) {
            int i = b * 256 + threadIdx.x;       // B*512/4 elems of float4
            int base = i * 4;
            int c = base & 511;
            float4 xv = *(const float4*)(features + base);
            f16x4 hv;
            float s0 = bn0_g[c]     * rsqrtf(bn0_v[c]     + EPS_BN);
            float s1 = bn0_g[c + 1] * rsqrtf(bn0_v[c + 1] + EPS_BN);
            float s2 = bn0_g[c + 2] * rsqrtf(bn0_v[c + 2] + EPS_BN);
            float s3 = bn0_g[c + 3] * rsqrtf(bn0_v[c + 3] + EPS_BN);
            hv.x = (f16)((xv.x - bn0_m[c])     * s0 + bn0_b[c]);
            hv.y = (f16)((xv.y - bn0_m[c + 1]) * s1 + bn0_b[c + 1]);
            hv.z = (f16)((xv.z - bn0_m[c + 2]) * s2 + bn0_b[c + 2]);
            hv.w = (f16)((xv.w - bn0_m[c + 3]) * s3 + bn0_b[c + 3]);
            *(f16x4*)(feats + base) = hv;
        } else {
            int i = (b - 16384) * 256 + threadIdx.x;   // B*128/4 float4
            ((float4*)oacc)[i] = make_float4(0.f, 0.f, 0.f, 0.f);
        }
    }
}

// ---------------- conveyor fp16 MFMA GEMM (measured optimum: 2 blocks/CU, 1 round) ----------------
// grid 512 (2/CU x 256 CU, one scheduling round), 512 threads = 8 waves
// (4 row x 2 col, 64x64 each). Block = 256 rows x 128 cols. 3-slot x 24KB LDS
// ring (72KB -> 2 blocks/CU), counted vmcnt: wait vmcnt(3) leaves next stage's
// 3 loads in flight. Ring slot s%3 overwritten by STAGE(s+2) only after the
// barrier proving all waves consumed stage s-1.
// MODE 0: out = glu(bn(A@W)) -> [B][256]; MODE 1: + res*sqrt(.5);
// MODE 2: MODE1, oc>=128 -> xhalf[B][128], oc<128 -> oacc += relu (if oacc).
template<int MODE, int NT>
__global__ __launch_bounds__(512, 4) void gemm_conveyor(
    const f16* __restrict__ A, const int ldA,      // K = NT*32
    const f16* __restrict__ B,                     // [512][K] f16, glu_perm2 rows
    const float* __restrict__ scale, const float* __restrict__ shift,
    const f16* __restrict__ res,
    f16* __restrict__ out,
    float* __restrict__ oacc)
{
    constexpr int K = NT * 32;
    __shared__ __align__(16) char smem[3 * 24576];
    const int tid  = threadIdx.x;
    const int lane = tid & 63;
    const int w    = tid >> 6;
    const int wm   = w >> 1;             // 0..3
    const int wn   = w & 1;              // 0..1
    const int lr   = lane & 15;
    const int lh   = lane >> 4;
    const int d    = blockIdx.x;
    const int bid  = (d & 7) * 64 + (d >> 3);    // XCD-bijective (512 = 8*64)
    const int row0 = (bid >> 2) * 256;
    const int bcol = (bid & 3) * 128;

    const int c0 = 3 * w, c1 = 3 * w + 1, c2 = 3 * w + 2;
    const bool a0 = c0 < 16, a1 = c1 < 16, a2 = c2 < 16;
    const char* p0 = a0 ? (const char*)(A + (size_t)(row0 + c0 * 16 + lr) * ldA + lh * 8)
                        : (const char*)(B + (size_t)(bcol + (c0 - 16) * 16 + lr) * K + lh * 8);
    const char* p1 = a1 ? (const char*)(A + (size_t)(row0 + c1 * 16 + lr) * ldA + lh * 8)
                        : (const char*)(B + (size_t)(bcol + (c1 - 16) * 16 + lr) * K + lh * 8);
    const char* p2 = a2 ? (const char*)(A + (size_t)(row0 + c2 * 16 + lr) * ldA + lh * 8)
                        : (const char*)(B + (size_t)(bcol + (c2 - 16) * 16 + lr) * K + lh * 8);
    const int d0 = c0 * 1024, d1 = c1 * 1024, d2 = c2 * 1024;

    f32x4 acc[4][4];
    #pragma unroll
    for (int m = 0; m < 4; ++m)
        #pragma unroll
        for (int n = 0; n < 4; ++n)
            acc[m][n] = f32x4{0.f, 0.f, 0.f, 0.f};

    auto STAGE = [&](int s) {
        const int ko = s * 64;                 // 32 f16 = 64 bytes per k-step
        char* ring = smem + (s % 3) * 24576;
        gload16(p0 + ko, ring + d0);
        gload16(p1 + ko, ring + d1);
        gload16(p2 + ko, ring + d2);
    };

    STAGE(0); STAGE(1);

    for (int s = 0; s < NT; ++s) {
        if (s + 1 < NT) asm volatile("s_waitcnt vmcnt(3)" ::: "memory");
        else            asm volatile("s_waitcnt vmcnt(0)" ::: "memory");
        __builtin_amdgcn_s_barrier();
        asm volatile("" ::: "memory");         // pin ds_reads below barrier
        if (s + 2 < NT) STAGE(s + 2);

        const char* L = smem + (s % 3) * 24576;
        f16x8 a[4], b[4];
        #pragma unroll
        for (int m = 0; m < 4; ++m)
            a[m] = *(const f16x8*)(L + (wm * 4 + m) * 1024 + lane * 16);
        #pragma unroll
        for (int n = 0; n < 4; ++n)
            b[n] = *(const f16x8*)(L + 16384 + (wn * 4 + n) * 1024 + lane * 16);
        __builtin_amdgcn_s_setprio(1);
        #pragma unroll
        for (int n = 0; n < 4; ++n)
            #pragma unroll
            for (int m = 0; m < 4; ++m)
                acc[m][n] = __builtin_amdgcn_mfma_f32_16x16x32_f16(a[m], b[n], acc[m][n], 0, 0, 0);
        __builtin_amdgcn_s_setprio(0);
    }

    // epilogue: fragment row' = (lane>>4)*4+r, col' = lane&15; GLU in-lane (permuted W)
    const int rbase = row0 + wm * 64;
    #pragma unroll
    for (int p = 0; p < 2; ++p) {
        const int cb = bcol + wn * 64 + p * 32;
        const float sA = scale[cb + lr],      hA = shift[cb + lr];
        const float sB = scale[cb + 16 + lr], hB = shift[cb + 16 + lr];
        const int oc = (cb >> 1) + lr;
        #pragma unroll
        for (int m = 0; m < 4; ++m) {
            #pragma unroll
            for (int r = 0; r < 4; ++r) {
                const int row = rbase + m * 16 + lh * 4 + r;
                float y0 = acc[m][2 * p][r]     * sA + hA;
                float y1 = acc[m][2 * p + 1][r] * sB + hB;
                float val = y0 / (1.f + expf(-y1));
                if constexpr (MODE >= 1)
                    val += SQRT_HALF * (float)res[(size_t)row * 256 + oc];
                if constexpr (MODE <= 1) {
                    out[(size_t)row * 256 + oc] = (f16)val;
                } else {
                    if (oc < 128) {
                        if (oacc) oacc[(size_t)row * 128 + oc] += fmaxf(val, 0.f);
                    } else {
                        out[(size_t)row * 128 + (oc - 128)] = (f16)val;
                    }
                }
            }
        }
    }
}

// ---------------- fused attention GEMM + sparsemax (Newton) + mf emission ----------------
// 64-row blocks, 512 threads (8 waves), grid 512, 2 blocks/CU (launch_bounds 4/EU),
// one round. XCD-bijective row swizzle matches the GEMMs (producer/consumer L2 locality).
template<int USE_PRIOR>
__global__ __launch_bounds__(512, 4) void att_sparsemax_kernel(
    const f16* __restrict__ A,               // xhalf [B][128]
    const f16* __restrict__ Bw,              // [512][128] f16
    const float* __restrict__ scale, const float* __restrict__ shift,
    const f16* __restrict__ feats,
    f16* __restrict__ prior,
    float* __restrict__ mask_out,
    f16* __restrict__ mf)
{
    __shared__ f16 attLds[64 * 512];         // 64 KB
    const int tid  = threadIdx.x;
    const int lane = tid & 63;
    const int w    = tid >> 6;               // 0..7
    const int dd   = blockIdx.x;
    const int bid  = (dd & 7) * 64 + (dd >> 3);  // same XCD mapping as gemm
    const int brow = bid * 64;
    const int lr   = lane & 15;
    const int lk   = (lane >> 4) * 8;

    f32x4 acc[4][4];
    #pragma unroll
    for (int m = 0; m < 4; ++m)
        #pragma unroll
        for (int n = 0; n < 4; ++n)
            acc[m][n] = f32x4{0.f, 0.f, 0.f, 0.f};

    const f16* pa = A + (size_t)(brow + lr) * 128 + lk;
    const f16* pb = Bw + (size_t)(w * 64 + lr) * 128 + lk;

    #pragma unroll
    for (int t = 0; t < 4; ++t) {
        f16x8 a[4], b[4];
        #pragma unroll
        for (int m = 0; m < 4; ++m) a[m] = *(const f16x8*)(pa + m * 16 * 128 + t * 32);
        #pragma unroll
        for (int n = 0; n < 4; ++n) b[n] = *(const f16x8*)(pb + n * 16 * 128 + t * 32);
        #pragma unroll
        for (int n = 0; n < 4; ++n)
            #pragma unroll
            for (int m = 0; m < 4; ++m)
                acc[m][n] = __builtin_amdgcn_mfma_f32_16x16x32_f16(a[m], b[n], acc[m][n], 0, 0, 0);
    }

    // bn'd att -> attLds (f16)
    #pragma unroll
    for (int n = 0; n < 4; ++n) {
        const int col = w * 64 + n * 16 + lr;
        const float s = scale[col], h = shift[col];
        #pragma unroll
        for (int m = 0; m < 4; ++m) {
            const int r0 = m * 16 + (lane >> 4) * 4;
            #pragma unroll
            for (int r = 0; r < 4; ++r)
                attLds[(r0 + r) * 512 + col] = (f16)(acc[m][n][r] * s + h);
        }
    }
    __syncthreads();

    // phase 2: wave w rows w*8..w*8+7; lane owns cols [8*lane, 8*lane+8)
    const int cb8 = lane * 8;
    for (int rr = 0; rr < 8; ++rr) {
        const int row = w * 8 + rr;
        const int grow = brow + row;
        const size_t g8 = (size_t)grow * 512 + cb8;

        float z[8], pr[8];
        f16x8 prv;
        if (USE_PRIOR) prv = *(const f16x8*)(prior + g8);
        f16x8 zv = *(const f16x8*)(&attLds[row * 512 + cb8]);
        #pragma unroll
        for (int j = 0; j < 8; ++j) {
            pr[j] = USE_PRIOR ? (float)prv[j] : 1.0f;
            z[j] = (float)zv[j] * pr[j];
        }
        float mx = z[0];
        #pragma unroll
        for (int j = 1; j < 8; ++j) mx = fmaxf(mx, z[j]);
        #pragma unroll
        for (int off = 32; off; off >>= 1) mx = fmaxf(mx, __shfl_xor(mx, off));

        float tau = mx - 1.0f;
        for (int it = 0; it < 20; ++it) {
            float s = 0.f, c = 0.f;
            #pragma unroll
            for (int j = 0; j < 8; ++j) {
                float dz = z[j] - tau;
                if (dz > 0.f) { s += dz; c += 1.f; }
            }
            #pragma unroll
            for (int off = 32; off; off >>= 1) {
                s += __shfl_xor(s, off);
                c += __shfl_xor(c, off);
            }
            float tn = tau + (s - 1.0f) / c;
            if (!(tn > tau)) break;
            tau = tn;
        }

        float mk[8];
        f16x8 pnew, mfv;
        f16x8 fv = *(const f16x8*)(feats + g8);
        #pragma unroll
        for (int j = 0; j < 8; ++j) {
            mk[j] = fmaxf(z[j] - tau, 0.f);
            pnew[j] = (f16)(pr[j] * (RELAX_C - mk[j]));
            mfv[j] = (f16)(mk[j] * (float)fv[j]);
        }
        f32x4 m0 = {mk[0], mk[1], mk[2], mk[3]};
        f32x4 m1 = {mk[4], mk[5], mk[6], mk[7]};
        __builtin_nontemporal_store(m0, (f32x4*)(mask_out + g8));
        __builtin_nontemporal_store(m1, (f32x4*)(mask_out + g8 + 4));
        *(f16x8*)(prior + g8) = pnew;
        *(f16x8*)(mf + g8) = mfv;
    }
}

// ---------------- final fp32 SIMT GEMM (K=128, N=128) ----------------
__global__ __launch_bounds__(256) void gemm_f32_final(
    const float* __restrict__ A,
    const float* __restrict__ W,
    const float* __restrict__ bias,
    float* __restrict__ out)
{
    __shared__ float As[16][128];
    __shared__ float Bs[16][128];
    const int tid = threadIdx.x;
    const int tm = tid >> 4, tn = tid & 15;
    const int brow = blockIdx.x * 128;
    float acc[8][8] = {};
    for (int k0 = 0; k0 < 128; k0 += 16) {
        #pragma unroll
        for (int i = 0; i < 2; ++i) {
            int f = tid + i * 256;
            int row = f >> 2, kq = (f & 3) << 2;
            float4 av = *(const float4*)(A + (size_t)(brow + row) * 128 + k0 + kq);
            As[kq + 0][row] = av.x;
            As[kq + 1][row] = av.y;
            As[kq + 2][row] = av.z;
            As[kq + 3][row] = av.w;
            int kr = f >> 5, nq = (f & 31) << 2;
            *(float4*)(&Bs[kr][nq]) = *(const float4*)(W + (size_t)(k0 + kr) * 128 + nq);
        }
        __syncthreads();
        #pragma unroll
        for (int kk = 0; kk < 16; ++kk) {
            float a[8], b[8];
            *(float4*)(a)     = *(const float4*)(&As[kk][tm * 8]);
            *(float4*)(a + 4) = *(const float4*)(&As[kk][tm * 8 + 4]);
            *(float4*)(b)     = *(const float4*)(&Bs[kk][tn * 8]);
            *(float4*)(b + 4) = *(const float4*)(&Bs[kk][tn * 8 + 4]);
            #pragma unroll
            for (int i = 0; i < 8; ++i)
                #pragma unroll
                for (int j = 0; j < 8; ++j)
                    acc[i][j] += a[i] * b[j];
        }
        __syncthreads();
    }
    #pragma unroll
    for (int i = 0; i < 8; ++i) {
        int row = brow + tm * 8 + i;
        #pragma unroll
        for (int j = 0; j < 8; ++j)
            out[(size_t)row * 128 + tn * 8 + j] = acc[i][j] + bias[tn * 8 + j];
    }
}

// ---------------- launch ----------------
extern "C" void kernel_launch(void* const* d_in, const int* in_sizes, int n_in,
                              void* d_out, int out_size, void* d_ws, size_t ws_size,
                              hipStream_t stream)
{
    const float* features = (const float*)d_in[0];
    const float* bn0_g = (const float*)d_in[1];
    const float* bn0_b = (const float*)d_in[2];
    const float* bn0_m = (const float*)d_in[3];
    const float* bn0_v = (const float*)d_in[4];
    const float* Ws0   = (const float*)d_in[5];
    const float* Ws1   = (const float*)d_in[6];
    const float* Wu    = (const float*)d_in[7];
    const float* ft_g  = (const float*)d_in[8];
    const float* ft_b  = (const float*)d_in[9];
    const float* ft_m  = (const float*)d_in[10];
    const float* ft_v  = (const float*)d_in[11];
    const float* W_att = (const float*)d_in[12];
    const float* att_g = (const float*)d_in[13];
    const float* att_b = (const float*)d_in[14];
    const float* att_m = (const float*)d_in[15];
    const float* att_v = (const float*)d_in[16];
    const float* Wf    = (const float*)d_in[17];
    const float* bf    = (const float*)d_in[18];
    float* out = (float*)d_out;

    // ---- ws layout (bytes) ----
    char* wp = (char*)d_ws;
    auto alloc = [&](size_t bytes) { char* r = wp; wp += (bytes + 255) & ~(size_t)255; return r; };
    const size_t BR = B_ROWS;
    f16* feats  = (f16*)alloc(BR * 512 * 2);
    f16* mfbuf  = (f16*)alloc(BR * 512 * 2);
    f16* ubuf   = (f16*)alloc(BR * 256 * 2);
    f16* vbuf   = (f16*)alloc(BR * 256 * 2);
    f16* xhalf  = (f16*)alloc(BR * 128 * 2);
    f16* prior  = (f16*)alloc(BR * 512 * 2);
    float* oacc  = (float*)alloc(BR * 128 * 4);
    f16* ws0  = (f16*)alloc(512 * 512 * 2);
    f16* ws1  = (f16*)alloc(512 * 256 * 2);
    f16* wu   = (f16*)alloc((size_t)12 * 512 * 256 * 2);
    f16* wat  = (f16*)alloc((size_t)5 * 512 * 128 * 2);
    float* ftS  = (float*)alloc(24 * 512 * 4);
    float* ftH  = (float*)alloc(24 * 512 * 4);
    float* attS = (float*)alloc(5 * 512 * 4);
    float* attH = (float*)alloc(5 * 512 * 4);

    // ---- prep (1 dispatch) ----
    prep_all<<<29500, 256, 0, stream>>>(
        bn0_g, bn0_b, bn0_m, bn0_v, ft_g, ft_b, ft_m, ft_v,
        att_g, att_b, att_m, att_v, Ws0, Ws1, Wu, W_att, features,
        ftS, ftH, attS, attH, ws0, ws1, wu, wat, feats, oacc);

    // transformer t: G1 (K=512) + G2..G4 (K=256) via 2-block/CU conveyor GEMMs
    auto ft = [&](const f16* in, int t, bool accum) {
        const f16* wu0 = wu + (size_t)(t * 2 + 0) * 131072;
        const f16* wu1 = wu + (size_t)(t * 2 + 1) * 131072;
        gemm_conveyor<0, 16><<<512, 512, 0, stream>>>(in, 512, ws0,
            ftS + (t * 4 + 0) * 512, ftH + (t * 4 + 0) * 512,
            nullptr, ubuf, nullptr);
        gemm_conveyor<1, 8><<<512, 512, 0, stream>>>(ubuf, 256, ws1,
            ftS + (t * 4 + 1) * 512, ftH + (t * 4 + 1) * 512,
            ubuf, vbuf, nullptr);
        gemm_conveyor<1, 8><<<512, 512, 0, stream>>>(vbuf, 256, wu0,
            ftS + (t * 4 + 2) * 512, ftH + (t * 4 + 2) * 512,
            vbuf, ubuf, nullptr);
        gemm_conveyor<2, 8><<<512, 512, 0, stream>>>(ubuf, 256, wu1,
            ftS + (t * 4 + 3) * 512, ftH + (t * 4 + 3) * 512,
            ubuf, xhalf, accum ? oacc : nullptr);
    };

    ft(feats, 0, false);

    for (int s = 0; s < NSTEPS; ++s) {
        float* mask_s = out + 4194304 + (size_t)s * 16777216;
        if (s == 0)
            att_sparsemax_kernel<0><<<512, 512, 0, stream>>>(
                xhalf, wat + (size_t)s * 65536,
                attS + s * 512, attH + s * 512,
                feats, prior, mask_s, mfbuf);
        else
            att_sparsemax_kernel<1><<<512, 512, 0, stream>>>(
                xhalf, wat + (size_t)s * 65536,
                attS + s * 512, attH + s * 512,
                feats, prior, mask_s, mfbuf);
        ft(mfbuf, s + 1, true);
    }

    gemm_f32_final<<<B_ROWS / 128, 256, 0, stream>>>(oacc, Wf, bf, out);
}